// Round 18
// baseline (639.408 us; speedup 1.0000x reference)
//
#include <hip/hip_runtime.h>

// ---------------------------------------------------------------------------
// GCN: 5x GCNConv + final linear.  N=100000, E=1.6M, D_IN=D_H=128, N_CLS=100.
//
// Collapsed algebra (R1-R3): h1 = relu(S x W1 + 1 b1^T),
//   out = S^4 h1 Wc + S^3 1 c2^T + S^2 1 c3^T + S 1 c4^T + 1 cb^T,
// weight chain fp32, separate small kernels.
// s_k = S^k 1 ride as feature cols 100..102.
// Feature buffers fp16 row-major, stride 128 (256B aligned rows).
// Matmuls: MFMA f32_16x16x32_f16.  Aggregation: TWO nodes per wave +
// col-index prefetch (~67us/pass, pinned at random-gather service rate;
// 5 passes are algorithmically minimal — the op applies S five times).
// R18: count/fill at 3 edges/thread (grid 8.3k waves ~= 8192 slots: max
// depth at saturation; depth-2=12.5k waves 67us, depth-8=3.1k waves 88us).
// ---------------------------------------------------------------------------

typedef _Float16 h16;
typedef _Float16 __attribute__((ext_vector_type(4))) h16x4;
typedef _Float16 __attribute__((ext_vector_type(8))) h16x8;
typedef float __attribute__((ext_vector_type(4))) f32x4;

static __device__ __forceinline__ int load_idx(const int* edge, const int* flag, size_t pos) {
  bool is64 = (*flag == 0);
  if (is64) return (int)((const long long*)edge)[pos];
  return edge[pos];
}

// ---- edge dtype detection: if input is int64, odd int32 slots (hi words) are 0
__global__ void k_detect(const int* __restrict__ edge, int* __restrict__ flag) {
  int t = threadIdx.x;
  if (edge[2 * t + 1] != 0) atomicOr(flag, 1);
}

// count degrees (3 edges/thread, saturated grid), record rank, compact dst
__global__ void k_count(const int* __restrict__ edge, const int* __restrict__ flag,
                        int* __restrict__ counts, int* __restrict__ rank,
                        int* __restrict__ dstc, int E) {
  int base = (blockIdx.x * 256 + threadIdx.x) * 3;
  if (base >= E) return;
  int m = (E - base < 3) ? (E - base) : 3;
  int d[3], r[3];
#pragma unroll
  for (int j = 0; j < 3; ++j)
    d[j] = (j < m) ? load_idx(edge, flag, (size_t)E + base + j) : 0;
#pragma unroll
  for (int j = 0; j < 3; ++j)
    if (j < m) dstc[base + j] = d[j];
#pragma unroll
  for (int j = 0; j < 3; ++j)
    r[j] = (j < m) ? atomicAdd(&counts[d[j]], 1) : 0;
#pragma unroll
  for (int j = 0; j < 3; ++j)
    if (j < m) rank[base + j] = r[j];
}

// ---- CSR build: chunk sums -> root scan -> per-chunk rescan ----
__global__ void k_chunksum(const int* __restrict__ counts, int* __restrict__ chunksums, int n) {
  __shared__ int sd[256];
  int t = threadIdx.x;
  int base = blockIdx.x * 1024 + t * 4;
  int s = 0;
#pragma unroll
  for (int j = 0; j < 4; ++j) { int i = base + j; if (i < n) s += counts[i]; }
  sd[t] = s; __syncthreads();
  for (int off = 128; off > 0; off >>= 1) {
    if (t < off) sd[t] += sd[t + off];
    __syncthreads();
  }
  if (t == 0) chunksums[blockIdx.x] = sd[0];
}

__global__ void k_root(const int* __restrict__ chunksums, int* __restrict__ chunkbase, int nchunks) {
  __shared__ int sc[128];
  int t = threadIdx.x;
  int v = (t < nchunks) ? chunksums[t] : 0;
  sc[t] = v; __syncthreads();
  for (int off = 1; off < 128; off <<= 1) {
    int x = (t >= off) ? sc[t - off] : 0;
    __syncthreads();
    sc[t] += x;
    __syncthreads();
  }
  if (t < nchunks) chunkbase[t] = sc[t] - v;
}

// scan + offsets + dinv
__global__ void k_scan3(const int* __restrict__ counts, const int* __restrict__ chunkbase,
                        int* __restrict__ offsets, float* __restrict__ dinv, int n, int E) {
  __shared__ int sd[256];
  int t = threadIdx.x;
  int base = blockIdx.x * 1024 + t * 4;
  int c[4]; int s = 0;
#pragma unroll
  for (int j = 0; j < 4; ++j) { int i = base + j; c[j] = (i < n) ? counts[i] : 0; s += c[j]; }
  sd[t] = s; __syncthreads();
  int v = s;
  for (int off = 1; off < 256; off <<= 1) {
    int x = (t >= off) ? sd[t - off] : 0;
    __syncthreads();
    sd[t] += x;
    __syncthreads();
  }
  int run = chunkbase[blockIdx.x] + sd[t] - v;
#pragma unroll
  for (int j = 0; j < 4; ++j) {
    int i = base + j;
    if (i < n) {
      offsets[i] = run;
      dinv[i] = rsqrtf((float)c[j] + 1.0f);
    }
    run += c[j];
  }
  if (blockIdx.x == 0 && t == 0) offsets[n] = E;
}

// atomic-free fill (3 edges/thread): position = offsets[dst] + rank
__global__ void k_fill(const int* __restrict__ edge, const int* __restrict__ flag,
                       const int* __restrict__ offsets, const int* __restrict__ rank,
                       const int* __restrict__ dstc, int* __restrict__ col, int E) {
  int base = (blockIdx.x * 256 + threadIdx.x) * 3;
  if (base >= E) return;
  int m = (E - base < 3) ? (E - base) : 3;
  int s[3], d[3], r[3], o[3];
#pragma unroll
  for (int j = 0; j < 3; ++j) s[j] = (j < m) ? load_idx(edge, flag, (size_t)base + j) : 0;
#pragma unroll
  for (int j = 0; j < 3; ++j) d[j] = (j < m) ? dstc[base + j] : 0;
#pragma unroll
  for (int j = 0; j < 3; ++j) r[j] = (j < m) ? rank[base + j] : 0;
#pragma unroll
  for (int j = 0; j < 3; ++j) o[j] = (j < m) ? offsets[d[j]] : 0;
#pragma unroll
  for (int j = 0; j < 3; ++j)
    if (j < m) col[o[j] + r[j]] = s[j];
}

// ---- small fp32 matmul for the weight chain: C[MxNc] = A[MxK] B[KxNc] ----
__global__ void k_smm(const float* __restrict__ A, const float* __restrict__ B,
                      float* __restrict__ C, int M, int K, int Nc) {
  int idx = blockIdx.x * 256 + threadIdx.x;
  if (idx >= M * Nc) return;
  int i = idx / Nc, j = idx % Nc;
  float acc = 0.f;
  for (int k = 0; k < K; ++k) acc = fmaf(A[i * K + k], B[k * Nc + j], acc);
  C[idx] = acc;
}

__global__ void k_cvec(const float* __restrict__ b2, const float* __restrict__ b3,
                       const float* __restrict__ b4, const float* __restrict__ b5,
                       const float* __restrict__ bl, const float* __restrict__ Wl,
                       const float* __restrict__ R3, const float* __restrict__ R4,
                       const float* __restrict__ R5, float* __restrict__ corr) {
  int j = threadIdx.x;
  if (j >= 100) return;
  float a2 = 0.f, a3 = 0.f, a4 = 0.f, acb = 0.f;
  for (int k = 0; k < 128; ++k) {
    a2 = fmaf(b2[k], R3[k * 100 + j], a2);
    a3 = fmaf(b3[k], R4[k * 100 + j], a3);
    a4 = fmaf(b4[k], R5[k * 100 + j], a4);
  }
  for (int k = 0; k < 100; ++k) acb = fmaf(b5[k], Wl[k * 100 + j], acb);
  corr[j] = a2; corr[128 + j] = a3; corr[256 + j] = a4; corr[384 + j] = acb + bl[j];
}

// ---- MFMA matmul: out[r][c] = (X@W)[r][c]*dinv[r], fp16 out, stride OS=128.
template <typename TX, int M, int AUG>
__launch_bounds__(256)
__global__ void k_mm(const TX* __restrict__ X, const float* __restrict__ W,
                     const float* __restrict__ dinv, h16* __restrict__ out, int n) {
  const int K = 128, OS = 128;
  __shared__ h16 Xs[128 * 40];
  __shared__ h16 Wt[128 * 40];
  __shared__ float dv[128];
  int tid = threadIdx.x;
  int row0 = blockIdx.x * 128;
  int w = tid >> 6, lane = tid & 63;
  int lhi = lane >> 4, llo = lane & 15;

  if (tid < 128) dv[tid] = (row0 + tid < n) ? dinv[row0 + tid] : 0.f;

  f32x4 acc[2][8];
#pragma unroll
  for (int fr = 0; fr < 2; ++fr)
#pragma unroll
    for (int fc = 0; fc < 8; ++fc) {
      f32x4 z = {0.f, 0.f, 0.f, 0.f};
      acc[fr][fc] = z;
    }

  for (int kc = 0; kc < K; kc += 32) {
    __syncthreads();
    if (sizeof(TX) == 4) {
      for (int idx = tid * 4; idx < 128 * 32; idx += 1024) {
        int r = idx >> 5, c = idx & 31;
        f32x4 v = {0.f, 0.f, 0.f, 0.f};
        if (row0 + r < n)
          v = __builtin_nontemporal_load(
              (const f32x4*)&((const float*)X)[(size_t)(row0 + r) * K + kc + c]);
        h16x4 h = {(h16)v[0], (h16)v[1], (h16)v[2], (h16)v[3]};
        *(h16x4*)&Xs[r * 40 + c] = h;
      }
    } else {
      for (int idx = tid * 8; idx < 128 * 32; idx += 2048) {
        int r = idx >> 5, c = idx & 31;
        h16x8 v = {(h16)0.f, (h16)0.f, (h16)0.f, (h16)0.f,
                   (h16)0.f, (h16)0.f, (h16)0.f, (h16)0.f};
        if (row0 + r < n)
          v = __builtin_nontemporal_load(
              (const h16x8*)&((const h16*)X)[(size_t)(row0 + r) * K + kc + c]);
        *(h16x8*)&Xs[r * 40 + c] = v;
      }
    }
    for (int idx = tid * 4; idx < 32 * 128; idx += 1024) {
      int k = idx >> 7, nn = idx & 127;
      float4 v = make_float4(0.f, 0.f, 0.f, 0.f);
      if (nn < M) v = *(const float4*)&W[(size_t)(kc + k) * M + nn];
      Wt[(nn + 0) * 40 + k] = (h16)v.x;
      Wt[(nn + 1) * 40 + k] = (h16)v.y;
      Wt[(nn + 2) * 40 + k] = (h16)v.z;
      Wt[(nn + 3) * 40 + k] = (h16)v.w;
    }
    __syncthreads();

    h16x8 af0 = *(const h16x8*)&Xs[(w * 32 + llo) * 40 + lhi * 8];
    h16x8 af1 = *(const h16x8*)&Xs[(w * 32 + 16 + llo) * 40 + lhi * 8];
#pragma unroll
    for (int fc = 0; fc < 8; ++fc) {
      h16x8 bf = *(const h16x8*)&Wt[(fc * 16 + llo) * 40 + lhi * 8];
      acc[0][fc] = __builtin_amdgcn_mfma_f32_16x16x32_f16(af0, bf, acc[0][fc], 0, 0, 0);
      acc[1][fc] = __builtin_amdgcn_mfma_f32_16x16x32_f16(af1, bf, acc[1][fc], 0, 0, 0);
    }
  }

#pragma unroll
  for (int fr = 0; fr < 2; ++fr) {
#pragma unroll
    for (int r = 0; r < 4; ++r) {
      int lrow = w * 32 + fr * 16 + lhi * 4 + r;
      int grow = row0 + lrow;
      if (grow >= n) continue;
      float sc = dv[lrow];
#pragma unroll
      for (int fc = 0; fc < 8; ++fc) {
        int colj = fc * 16 + llo;
        float vv = (colj < M) ? acc[fr][fc][r] * sc
                 : ((AUG && colj == 100) ? sc : 0.f);
        out[(size_t)grow * OS + colj] = (h16)vv;
      }
    }
  }
}

// ---- aggregation: TWO nodes per wave, col-prefetch pipelined.
// MODE 0: relu(dinv*(sum+self)+bias)  [width 128]
// MODE 1: dinv^2*(sum+self) (pre-scaled), fresh col seeded = dinv [width 104]
// MODE 2: final + rank-1 corrections -> fp32 out [n][100]  [width 100]
template <int WIDTH, int MODE>
__global__ void k_agg(const h16* __restrict__ hs, const int* __restrict__ offsets,
                      const int* __restrict__ col, const float* __restrict__ dinv,
                      const float* __restrict__ bias, const float* __restrict__ corr,
                      void* __restrict__ out, int n, int fresh) {
  const int STRIDE = 128;
  int gw = (blockIdx.x * 256 + threadIdx.x) >> 6;   // global wave id
  int lane = threadIdx.x & 63;
  int half = lane >> 5, sl = lane & 31;
  int v = gw * 2 + half;
  int c = sl * 4;
  if (v >= n) return;
  if (c >= WIDTH) return;
  const h16* row = &hs[(size_t)v * STRIDE];
  h16x4 selfv = *(const h16x4*)&row[c];
  float a0 = (float)selfv[0], a1 = (float)selfv[1];
  float a2 = (float)selfv[2], a3 = (float)selfv[3];
  int s = offsets[v], e = offsets[v + 1];
  int cc[16];
#pragma unroll
  for (int j = 0; j < 16; ++j) cc[j] = (s + j < e) ? col[s + j] : -1;
  for (int i = s; i < e; i += 16) {
    int cn[16];
#pragma unroll
    for (int j = 0; j < 16; ++j) {
      int idx = i + 16 + j;
      cn[j] = (idx < e) ? col[idx] : -1;     // prefetch next group's indices
    }
    h16x4 m[16];
#pragma unroll
    for (int j = 0; j < 16; ++j) {
      h16x4 z = {(h16)0.f, (h16)0.f, (h16)0.f, (h16)0.f};
      m[j] = z;
      if (cc[j] >= 0)
        m[j] = *(const h16x4*)&hs[(size_t)cc[j] * STRIDE + c];
    }
#pragma unroll
    for (int j = 0; j < 16; ++j) {
      a0 += (float)m[j][0]; a1 += (float)m[j][1];
      a2 += (float)m[j][2]; a3 += (float)m[j][3];
    }
#pragma unroll
    for (int j = 0; j < 16; ++j) cc[j] = cn[j];
  }
  float w = dinv[v];
  if (MODE == 0) {
    float r0 = fmaxf(fmaf(a0, w, bias[c]),     0.f);
    float r1 = fmaxf(fmaf(a1, w, bias[c + 1]), 0.f);
    float r2 = fmaxf(fmaf(a2, w, bias[c + 2]), 0.f);
    float r3 = fmaxf(fmaf(a3, w, bias[c + 3]), 0.f);
    h16x4 p = {(h16)r0, (h16)r1, (h16)r2, (h16)r3};
    *(h16x4*)&((h16*)out)[(size_t)v * STRIDE + c] = p;
  } else if (MODE == 1) {
    float w2 = w * w;
    float r0 = a0 * w2, r1 = a1 * w2, r2 = a2 * w2, r3 = a3 * w2;
    if (c == fresh) r0 = w;
    else if (c + 1 == fresh) r1 = w;
    else if (c + 2 == fresh) r2 = w;
    else if (c + 3 == fresh) r3 = w;
    h16x4 p = {(h16)r0, (h16)r1, (h16)r2, (h16)r3};
    *(h16x4*)&((h16*)out)[(size_t)v * STRIDE + c] = p;
  } else {
    float inv_w = 1.0f / w;
    float v3 = (float)row[100] * inv_w;
    float v2 = (float)row[101] * inv_w;
    float v1 = (float)row[102] * inv_w;
    float r[4] = {a0, a1, a2, a3};
    float4 o;
    float* op = &o.x;
#pragma unroll
    for (int q = 0; q < 4; ++q) {
      op[q] = r[q] * w + v3 * corr[c + q] + v2 * corr[128 + c + q]
            + v1 * corr[256 + c + q] + corr[384 + c + q];
    }
    *(float4*)&((float*)out)[(size_t)v * 100 + c] = o;
  }
}

// ---------------------------------------------------------------------------
extern "C" void kernel_launch(void* const* d_in, const int* in_sizes, int n_in,
                              void* d_out, int out_size, void* d_ws, size_t ws_size,
                              hipStream_t stream) {
  const float* x    = (const float*)d_in[0];
  const int*   edge = (const int*)d_in[1];
  const float* W1 = (const float*)d_in[2];  const float* b1 = (const float*)d_in[3];
  const float* W2 = (const float*)d_in[4];  const float* b2 = (const float*)d_in[5];
  const float* W3 = (const float*)d_in[6];  const float* b3 = (const float*)d_in[7];
  const float* W4 = (const float*)d_in[8];  const float* b4 = (const float*)d_in[9];
  const float* W5 = (const float*)d_in[10]; const float* b5 = (const float*)d_in[11];
  const float* Wl = (const float*)d_in[12]; const float* bl = (const float*)d_in[13];

  const int N = in_sizes[0] / 128;
  const int E = in_sizes[1] / 2;

  char* ws = (char*)d_ws;
  size_t cur = 0;
  auto alloc = [&](size_t bytes) -> char* {
    char* p = ws + cur;
    cur = (cur + bytes + 255) & ~(size_t)255;
    return p;
  };
  int*    counts    = (int*)alloc((size_t)N * 4);
  int*    flag      = (int*)alloc(4);
  int*    offsets   = (int*)alloc((size_t)(N + 1) * 4);
  float*  dinv      = (float*)alloc((size_t)N * 4);
  int*    chunksums = (int*)alloc(128 * 4);
  int*    chunkbase = (int*)alloc(128 * 4);
  float*  R5        = (float*)alloc(128 * 100 * 4);
  float*  R4        = (float*)alloc(128 * 100 * 4);
  float*  R3        = (float*)alloc(128 * 100 * 4);
  float*  Wc        = (float*)alloc(128 * 100 * 4);
  float*  corr      = (float*)alloc(512 * 4);
  int*    rank      = (int*)alloc((size_t)E * 4);
  int*    dstc      = (int*)alloc((size_t)E * 4);
  int*    col       = (int*)alloc(((size_t)E + 32) * 4);  // +pad for group reads
  h16*    bufA      = (h16*)alloc((size_t)N * 128 * 2);   // stride 128, 256B rows
  h16*    bufB      = (h16*)alloc((size_t)N * 128 * 2);
  (void)ws_size; (void)n_in; (void)out_size;

  hipMemsetAsync(counts, 0, (size_t)N * 4, stream);
  hipMemsetAsync(flag, 0, 4, stream);

  const int nchunks = (N + 1023) / 1024;
  const int e3grid = (E + 767) / 768;   // 3 edges/thread: ~8.3k waves ~= slots

  k_detect<<<1, 256, 0, stream>>>(edge, flag);
  k_count<<<e3grid, 256, 0, stream>>>(edge, flag, counts, rank, dstc, E);
  k_chunksum<<<nchunks, 256, 0, stream>>>(counts, chunksums, N);
  k_root<<<1, 128, 0, stream>>>(chunksums, chunkbase, nchunks);
  k_scan3<<<nchunks, 256, 0, stream>>>(counts, chunkbase, offsets, dinv, N, E);
  k_fill<<<e3grid, 256, 0, stream>>>(edge, flag, offsets, rank, dstc, col, E);

  // weight chain (fp32, separate small kernels)
  const int sgrid = (128 * 100 + 255) / 256;
  k_smm<<<sgrid, 256, 0, stream>>>(W5, Wl, R5, 128, 100, 100);
  k_smm<<<sgrid, 256, 0, stream>>>(W4, R5, R4, 128, 128, 100);
  k_smm<<<sgrid, 256, 0, stream>>>(W3, R4, R3, 128, 128, 100);
  k_smm<<<sgrid, 256, 0, stream>>>(W2, R3, Wc, 128, 128, 100);
  k_cvec<<<1, 128, 0, stream>>>(b2, b3, b4, b5, bl, Wl, R3, R4, R5, corr);

  const int mmgrid = (N + 127) / 128;
  const int agrid = (N + 7) / 8;   // 2 nodes/wave, 4 waves/block

  // hs0 = (x W1) * dinv  [fp16, stride 128]  (MFMA)
  k_mm<float, 128, 0><<<mmgrid, 256, 0, stream>>>(x, W1, dinv, bufA, N);
  // h1 = relu(dinv*(gather+self) + b1)  [fp16, stride 128]
  k_agg<128, 0><<<agrid, 256, 0, stream>>>(bufA, offsets, col, dinv, b1, nullptr, bufB, N, 0);
  // g_scaled = (h1 Wc) * dinv, col100 = dinv seed  [fp16, stride 128]  (MFMA)
  k_mm<h16, 100, 1><<<mmgrid, 256, 0, stream>>>(bufB, Wc, dinv, bufA, N);
  // three chained S applications (pre-scaled); s-chain in cols 100..102
  k_agg<104, 1><<<agrid, 256, 0, stream>>>(bufA, offsets, col, dinv, nullptr, nullptr, bufB, N, 101);
  k_agg<104, 1><<<agrid, 256, 0, stream>>>(bufB, offsets, col, dinv, nullptr, nullptr, bufA, N, 102);
  k_agg<104, 1><<<agrid, 256, 0, stream>>>(bufA, offsets, col, dinv, nullptr, nullptr, bufB, N, -1);
  // final S application + corrections -> d_out [fp32, N x 100]
  k_agg<100, 2><<<agrid, 256, 0, stream>>>(bufB, offsets, col, dinv, nullptr, corr, (float*)d_out, N, -1);
}

// Round 19
// 626.492 us; speedup vs baseline: 1.0206x; 1.0206x over previous
//
#include <hip/hip_runtime.h>

// ---------------------------------------------------------------------------
// GCN: 5x GCNConv + final linear.  N=100000, E=1.6M, D_IN=D_H=128, N_CLS=100.
//
// Collapsed algebra (R1-R3): h1 = relu(S x W1 + 1 b1^T),
//   out = S^4 h1 Wc + S^3 1 c2^T + S^2 1 c3^T + S 1 c4^T + 1 cb^T,
// weight chain fp32, separate small kernels.
// s_k = S^k 1 ride as feature cols 100..102.
// Feature buffers fp16 row-major, stride 128 (256B aligned rows).
// Matmuls: MFMA f32_16x16x32_f16.  Aggregation: TWO nodes per wave +
// col-index prefetch (~67us/pass, pinned at random-gather service rate;
// 5 S-applications are algorithmically minimal).
// count/fill at 2 edges/thread — BRACKETED OPTIMUM (d1=79, d2=67.5, d3=84,
// d8=88us): depth-2 keeps 1.5x wave oversubscription.
// ---------------------------------------------------------------------------

typedef _Float16 h16;
typedef _Float16 __attribute__((ext_vector_type(4))) h16x4;
typedef _Float16 __attribute__((ext_vector_type(8))) h16x8;
typedef float __attribute__((ext_vector_type(4))) f32x4;

static __device__ __forceinline__ int load_idx(const int* edge, const int* flag, size_t pos) {
  bool is64 = (*flag == 0);
  if (is64) return (int)((const long long*)edge)[pos];
  return edge[pos];
}

// ---- edge dtype detection: if input is int64, odd int32 slots (hi words) are 0
__global__ void k_detect(const int* __restrict__ edge, int* __restrict__ flag) {
  int t = threadIdx.x;
  if (edge[2 * t + 1] != 0) atomicOr(flag, 1);
}

// count degrees (2 edges/thread, full occupancy), record rank, emit compact dst
__global__ void k_count(const int* __restrict__ edge, const int* __restrict__ flag,
                        int* __restrict__ counts, int* __restrict__ rank,
                        int* __restrict__ dstc, int E) {
  int base = (blockIdx.x * 256 + threadIdx.x) * 2;
  if (base >= E) return;
  int m = (E - base < 2) ? (E - base) : 2;
  int d0 = load_idx(edge, flag, (size_t)E + base);
  int d1 = (m > 1) ? load_idx(edge, flag, (size_t)E + base + 1) : 0;
  dstc[base] = d0;
  if (m > 1) dstc[base + 1] = d1;
  int r0 = atomicAdd(&counts[d0], 1);
  int r1 = (m > 1) ? atomicAdd(&counts[d1], 1) : 0;
  rank[base] = r0;
  if (m > 1) rank[base + 1] = r1;
}

// ---- CSR build: chunk sums -> root scan -> per-chunk rescan ----
__global__ void k_chunksum(const int* __restrict__ counts, int* __restrict__ chunksums, int n) {
  __shared__ int sd[256];
  int t = threadIdx.x;
  int base = blockIdx.x * 1024 + t * 4;
  int s = 0;
#pragma unroll
  for (int j = 0; j < 4; ++j) { int i = base + j; if (i < n) s += counts[i]; }
  sd[t] = s; __syncthreads();
  for (int off = 128; off > 0; off >>= 1) {
    if (t < off) sd[t] += sd[t + off];
    __syncthreads();
  }
  if (t == 0) chunksums[blockIdx.x] = sd[0];
}

__global__ void k_root(const int* __restrict__ chunksums, int* __restrict__ chunkbase, int nchunks) {
  __shared__ int sc[128];
  int t = threadIdx.x;
  int v = (t < nchunks) ? chunksums[t] : 0;
  sc[t] = v; __syncthreads();
  for (int off = 1; off < 128; off <<= 1) {
    int x = (t >= off) ? sc[t - off] : 0;
    __syncthreads();
    sc[t] += x;
    __syncthreads();
  }
  if (t < nchunks) chunkbase[t] = sc[t] - v;
}

// scan + offsets + dinv
__global__ void k_scan3(const int* __restrict__ counts, const int* __restrict__ chunkbase,
                        int* __restrict__ offsets, float* __restrict__ dinv, int n, int E) {
  __shared__ int sd[256];
  int t = threadIdx.x;
  int base = blockIdx.x * 1024 + t * 4;
  int c[4]; int s = 0;
#pragma unroll
  for (int j = 0; j < 4; ++j) { int i = base + j; c[j] = (i < n) ? counts[i] : 0; s += c[j]; }
  sd[t] = s; __syncthreads();
  int v = s;
  for (int off = 1; off < 256; off <<= 1) {
    int x = (t >= off) ? sd[t - off] : 0;
    __syncthreads();
    sd[t] += x;
    __syncthreads();
  }
  int run = chunkbase[blockIdx.x] + sd[t] - v;
#pragma unroll
  for (int j = 0; j < 4; ++j) {
    int i = base + j;
    if (i < n) {
      offsets[i] = run;
      dinv[i] = rsqrtf((float)c[j] + 1.0f);
    }
    run += c[j];
  }
  if (blockIdx.x == 0 && t == 0) offsets[n] = E;
}

// atomic-free fill (2 edges/thread): position = offsets[dst] + rank
__global__ void k_fill(const int* __restrict__ edge, const int* __restrict__ flag,
                       const int* __restrict__ offsets, const int* __restrict__ rank,
                       const int* __restrict__ dstc, int* __restrict__ col, int E) {
  int base = (blockIdx.x * 256 + threadIdx.x) * 2;
  if (base >= E) return;
  int m = (E - base < 2) ? (E - base) : 2;
  int s0 = load_idx(edge, flag, (size_t)base);
  int s1 = (m > 1) ? load_idx(edge, flag, (size_t)base + 1) : 0;
  int d0 = dstc[base];
  int d1 = (m > 1) ? dstc[base + 1] : 0;
  int r0 = rank[base];
  int r1 = (m > 1) ? rank[base + 1] : 0;
  int o0 = offsets[d0];
  int o1 = (m > 1) ? offsets[d1] : 0;
  col[o0 + r0] = s0;
  if (m > 1) col[o1 + r1] = s1;
}

// ---- small fp32 matmul for the weight chain: C[MxNc] = A[MxK] B[KxNc] ----
__global__ void k_smm(const float* __restrict__ A, const float* __restrict__ B,
                      float* __restrict__ C, int M, int K, int Nc) {
  int idx = blockIdx.x * 256 + threadIdx.x;
  if (idx >= M * Nc) return;
  int i = idx / Nc, j = idx % Nc;
  float acc = 0.f;
  for (int k = 0; k < K; ++k) acc = fmaf(A[i * K + k], B[k * Nc + j], acc);
  C[idx] = acc;
}

__global__ void k_cvec(const float* __restrict__ b2, const float* __restrict__ b3,
                       const float* __restrict__ b4, const float* __restrict__ b5,
                       const float* __restrict__ bl, const float* __restrict__ Wl,
                       const float* __restrict__ R3, const float* __restrict__ R4,
                       const float* __restrict__ R5, float* __restrict__ corr) {
  int j = threadIdx.x;
  if (j >= 100) return;
  float a2 = 0.f, a3 = 0.f, a4 = 0.f, acb = 0.f;
  for (int k = 0; k < 128; ++k) {
    a2 = fmaf(b2[k], R3[k * 100 + j], a2);
    a3 = fmaf(b3[k], R4[k * 100 + j], a3);
    a4 = fmaf(b4[k], R5[k * 100 + j], a4);
  }
  for (int k = 0; k < 100; ++k) acb = fmaf(b5[k], Wl[k * 100 + j], acb);
  corr[j] = a2; corr[128 + j] = a3; corr[256 + j] = a4; corr[384 + j] = acb + bl[j];
}

// ---- MFMA matmul: out[r][c] = (X@W)[r][c]*dinv[r], fp16 out, stride OS=128.
template <typename TX, int M, int AUG>
__launch_bounds__(256)
__global__ void k_mm(const TX* __restrict__ X, const float* __restrict__ W,
                     const float* __restrict__ dinv, h16* __restrict__ out, int n) {
  const int K = 128, OS = 128;
  __shared__ h16 Xs[128 * 40];
  __shared__ h16 Wt[128 * 40];
  __shared__ float dv[128];
  int tid = threadIdx.x;
  int row0 = blockIdx.x * 128;
  int w = tid >> 6, lane = tid & 63;
  int lhi = lane >> 4, llo = lane & 15;

  if (tid < 128) dv[tid] = (row0 + tid < n) ? dinv[row0 + tid] : 0.f;

  f32x4 acc[2][8];
#pragma unroll
  for (int fr = 0; fr < 2; ++fr)
#pragma unroll
    for (int fc = 0; fc < 8; ++fc) {
      f32x4 z = {0.f, 0.f, 0.f, 0.f};
      acc[fr][fc] = z;
    }

  for (int kc = 0; kc < K; kc += 32) {
    __syncthreads();
    if (sizeof(TX) == 4) {
      for (int idx = tid * 4; idx < 128 * 32; idx += 1024) {
        int r = idx >> 5, c = idx & 31;
        f32x4 v = {0.f, 0.f, 0.f, 0.f};
        if (row0 + r < n)
          v = __builtin_nontemporal_load(
              (const f32x4*)&((const float*)X)[(size_t)(row0 + r) * K + kc + c]);
        h16x4 h = {(h16)v[0], (h16)v[1], (h16)v[2], (h16)v[3]};
        *(h16x4*)&Xs[r * 40 + c] = h;
      }
    } else {
      for (int idx = tid * 8; idx < 128 * 32; idx += 2048) {
        int r = idx >> 5, c = idx & 31;
        h16x8 v = {(h16)0.f, (h16)0.f, (h16)0.f, (h16)0.f,
                   (h16)0.f, (h16)0.f, (h16)0.f, (h16)0.f};
        if (row0 + r < n)
          v = __builtin_nontemporal_load(
              (const h16x8*)&((const h16*)X)[(size_t)(row0 + r) * K + kc + c]);
        *(h16x8*)&Xs[r * 40 + c] = v;
      }
    }
    for (int idx = tid * 4; idx < 32 * 128; idx += 1024) {
      int k = idx >> 7, nn = idx & 127;
      float4 v = make_float4(0.f, 0.f, 0.f, 0.f);
      if (nn < M) v = *(const float4*)&W[(size_t)(kc + k) * M + nn];
      Wt[(nn + 0) * 40 + k] = (h16)v.x;
      Wt[(nn + 1) * 40 + k] = (h16)v.y;
      Wt[(nn + 2) * 40 + k] = (h16)v.z;
      Wt[(nn + 3) * 40 + k] = (h16)v.w;
    }
    __syncthreads();

    h16x8 af0 = *(const h16x8*)&Xs[(w * 32 + llo) * 40 + lhi * 8];
    h16x8 af1 = *(const h16x8*)&Xs[(w * 32 + 16 + llo) * 40 + lhi * 8];
#pragma unroll
    for (int fc = 0; fc < 8; ++fc) {
      h16x8 bf = *(const h16x8*)&Wt[(fc * 16 + llo) * 40 + lhi * 8];
      acc[0][fc] = __builtin_amdgcn_mfma_f32_16x16x32_f16(af0, bf, acc[0][fc], 0, 0, 0);
      acc[1][fc] = __builtin_amdgcn_mfma_f32_16x16x32_f16(af1, bf, acc[1][fc], 0, 0, 0);
    }
  }

#pragma unroll
  for (int fr = 0; fr < 2; ++fr) {
#pragma unroll
    for (int r = 0; r < 4; ++r) {
      int lrow = w * 32 + fr * 16 + lhi * 4 + r;
      int grow = row0 + lrow;
      if (grow >= n) continue;
      float sc = dv[lrow];
#pragma unroll
      for (int fc = 0; fc < 8; ++fc) {
        int colj = fc * 16 + llo;
        float vv = (colj < M) ? acc[fr][fc][r] * sc
                 : ((AUG && colj == 100) ? sc : 0.f);
        out[(size_t)grow * OS + colj] = (h16)vv;
      }
    }
  }
}

// ---- aggregation: TWO nodes per wave, col-prefetch pipelined.
// MODE 0: relu(dinv*(sum+self)+bias)  [width 128]
// MODE 1: dinv^2*(sum+self) (pre-scaled), fresh col seeded = dinv [width 104]
// MODE 2: final + rank-1 corrections -> fp32 out [n][100]  [width 100]
template <int WIDTH, int MODE>
__global__ void k_agg(const h16* __restrict__ hs, const int* __restrict__ offsets,
                      const int* __restrict__ col, const float* __restrict__ dinv,
                      const float* __restrict__ bias, const float* __restrict__ corr,
                      void* __restrict__ out, int n, int fresh) {
  const int STRIDE = 128;
  int gw = (blockIdx.x * 256 + threadIdx.x) >> 6;   // global wave id
  int lane = threadIdx.x & 63;
  int half = lane >> 5, sl = lane & 31;
  int v = gw * 2 + half;
  int c = sl * 4;
  if (v >= n) return;
  if (c >= WIDTH) return;
  const h16* row = &hs[(size_t)v * STRIDE];
  h16x4 selfv = *(const h16x4*)&row[c];
  float a0 = (float)selfv[0], a1 = (float)selfv[1];
  float a2 = (float)selfv[2], a3 = (float)selfv[3];
  int s = offsets[v], e = offsets[v + 1];
  int cc[16];
#pragma unroll
  for (int j = 0; j < 16; ++j) cc[j] = (s + j < e) ? col[s + j] : -1;
  for (int i = s; i < e; i += 16) {
    int cn[16];
#pragma unroll
    for (int j = 0; j < 16; ++j) {
      int idx = i + 16 + j;
      cn[j] = (idx < e) ? col[idx] : -1;     // prefetch next group's indices
    }
    h16x4 m[16];
#pragma unroll
    for (int j = 0; j < 16; ++j) {
      h16x4 z = {(h16)0.f, (h16)0.f, (h16)0.f, (h16)0.f};
      m[j] = z;
      if (cc[j] >= 0)
        m[j] = *(const h16x4*)&hs[(size_t)cc[j] * STRIDE + c];
    }
#pragma unroll
    for (int j = 0; j < 16; ++j) {
      a0 += (float)m[j][0]; a1 += (float)m[j][1];
      a2 += (float)m[j][2]; a3 += (float)m[j][3];
    }
#pragma unroll
    for (int j = 0; j < 16; ++j) cc[j] = cn[j];
  }
  float w = dinv[v];
  if (MODE == 0) {
    float r0 = fmaxf(fmaf(a0, w, bias[c]),     0.f);
    float r1 = fmaxf(fmaf(a1, w, bias[c + 1]), 0.f);
    float r2 = fmaxf(fmaf(a2, w, bias[c + 2]), 0.f);
    float r3 = fmaxf(fmaf(a3, w, bias[c + 3]), 0.f);
    h16x4 p = {(h16)r0, (h16)r1, (h16)r2, (h16)r3};
    *(h16x4*)&((h16*)out)[(size_t)v * STRIDE + c] = p;
  } else if (MODE == 1) {
    float w2 = w * w;
    float r0 = a0 * w2, r1 = a1 * w2, r2 = a2 * w2, r3 = a3 * w2;
    if (c == fresh) r0 = w;
    else if (c + 1 == fresh) r1 = w;
    else if (c + 2 == fresh) r2 = w;
    else if (c + 3 == fresh) r3 = w;
    h16x4 p = {(h16)r0, (h16)r1, (h16)r2, (h16)r3};
    *(h16x4*)&((h16*)out)[(size_t)v * STRIDE + c] = p;
  } else {
    float inv_w = 1.0f / w;
    float v3 = (float)row[100] * inv_w;
    float v2 = (float)row[101] * inv_w;
    float v1 = (float)row[102] * inv_w;
    float r[4] = {a0, a1, a2, a3};
    float4 o;
    float* op = &o.x;
#pragma unroll
    for (int q = 0; q < 4; ++q) {
      op[q] = r[q] * w + v3 * corr[c + q] + v2 * corr[128 + c + q]
            + v1 * corr[256 + c + q] + corr[384 + c + q];
    }
    *(float4*)&((float*)out)[(size_t)v * 100 + c] = o;
  }
}

// ---------------------------------------------------------------------------
extern "C" void kernel_launch(void* const* d_in, const int* in_sizes, int n_in,
                              void* d_out, int out_size, void* d_ws, size_t ws_size,
                              hipStream_t stream) {
  const float* x    = (const float*)d_in[0];
  const int*   edge = (const int*)d_in[1];
  const float* W1 = (const float*)d_in[2];  const float* b1 = (const float*)d_in[3];
  const float* W2 = (const float*)d_in[4];  const float* b2 = (const float*)d_in[5];
  const float* W3 = (const float*)d_in[6];  const float* b3 = (const float*)d_in[7];
  const float* W4 = (const float*)d_in[8];  const float* b4 = (const float*)d_in[9];
  const float* W5 = (const float*)d_in[10]; const float* b5 = (const float*)d_in[11];
  const float* Wl = (const float*)d_in[12]; const float* bl = (const float*)d_in[13];

  const int N = in_sizes[0] / 128;
  const int E = in_sizes[1] / 2;

  char* ws = (char*)d_ws;
  size_t cur = 0;
  auto alloc = [&](size_t bytes) -> char* {
    char* p = ws + cur;
    cur = (cur + bytes + 255) & ~(size_t)255;
    return p;
  };
  int*    counts    = (int*)alloc((size_t)N * 4);
  int*    flag      = (int*)alloc(4);
  int*    offsets   = (int*)alloc((size_t)(N + 1) * 4);
  float*  dinv      = (float*)alloc((size_t)N * 4);
  int*    chunksums = (int*)alloc(128 * 4);
  int*    chunkbase = (int*)alloc(128 * 4);
  float*  R5        = (float*)alloc(128 * 100 * 4);
  float*  R4        = (float*)alloc(128 * 100 * 4);
  float*  R3        = (float*)alloc(128 * 100 * 4);
  float*  Wc        = (float*)alloc(128 * 100 * 4);
  float*  corr      = (float*)alloc(512 * 4);
  int*    rank      = (int*)alloc((size_t)E * 4);
  int*    dstc      = (int*)alloc((size_t)E * 4);
  int*    col       = (int*)alloc(((size_t)E + 32) * 4);  // +pad for group reads
  h16*    bufA      = (h16*)alloc((size_t)N * 128 * 2);   // stride 128, 256B rows
  h16*    bufB      = (h16*)alloc((size_t)N * 128 * 2);
  (void)ws_size; (void)n_in; (void)out_size;

  hipMemsetAsync(counts, 0, (size_t)N * 4, stream);
  hipMemsetAsync(flag, 0, 4, stream);

  const int nchunks = (N + 1023) / 1024;
  const int e2grid = (E + 511) / 512;   // 2 edges/thread: bracketed optimum

  k_detect<<<1, 256, 0, stream>>>(edge, flag);
  k_count<<<e2grid, 256, 0, stream>>>(edge, flag, counts, rank, dstc, E);
  k_chunksum<<<nchunks, 256, 0, stream>>>(counts, chunksums, N);
  k_root<<<1, 128, 0, stream>>>(chunksums, chunkbase, nchunks);
  k_scan3<<<nchunks, 256, 0, stream>>>(counts, chunkbase, offsets, dinv, N, E);
  k_fill<<<e2grid, 256, 0, stream>>>(edge, flag, offsets, rank, dstc, col, E);

  // weight chain (fp32, separate small kernels)
  const int sgrid = (128 * 100 + 255) / 256;
  k_smm<<<sgrid, 256, 0, stream>>>(W5, Wl, R5, 128, 100, 100);
  k_smm<<<sgrid, 256, 0, stream>>>(W4, R5, R4, 128, 128, 100);
  k_smm<<<sgrid, 256, 0, stream>>>(W3, R4, R3, 128, 128, 100);
  k_smm<<<sgrid, 256, 0, stream>>>(W2, R3, Wc, 128, 128, 100);
  k_cvec<<<1, 128, 0, stream>>>(b2, b3, b4, b5, bl, Wl, R3, R4, R5, corr);

  const int mmgrid = (N + 127) / 128;
  const int agrid = (N + 7) / 8;   // 2 nodes/wave, 4 waves/block

  // hs0 = (x W1) * dinv  [fp16, stride 128]  (MFMA)
  k_mm<float, 128, 0><<<mmgrid, 256, 0, stream>>>(x, W1, dinv, bufA, N);
  // h1 = relu(dinv*(gather+self) + b1)  [fp16, stride 128]
  k_agg<128, 0><<<agrid, 256, 0, stream>>>(bufA, offsets, col, dinv, b1, nullptr, bufB, N, 0);
  // g_scaled = (h1 Wc) * dinv, col100 = dinv seed  [fp16, stride 128]  (MFMA)
  k_mm<h16, 100, 1><<<mmgrid, 256, 0, stream>>>(bufB, Wc, dinv, bufA, N);
  // three chained S applications (pre-scaled); s-chain in cols 100..102
  k_agg<104, 1><<<agrid, 256, 0, stream>>>(bufA, offsets, col, dinv, nullptr, nullptr, bufB, N, 101);
  k_agg<104, 1><<<agrid, 256, 0, stream>>>(bufB, offsets, col, dinv, nullptr, nullptr, bufA, N, 102);
  k_agg<104, 1><<<agrid, 256, 0, stream>>>(bufA, offsets, col, dinv, nullptr, nullptr, bufB, N, -1);
  // final S application + corrections -> d_out [fp32, N x 100]
  k_agg<100, 2><<<agrid, 256, 0, stream>>>(bufB, offsets, col, dinv, nullptr, corr, (float*)d_out, N, -1);
}